// Round 8
// baseline (10413.023 us; speedup 1.0000x reference)
//
#include <hip/hip_runtime.h>
#include <hip/hip_bf16.h>

#define N_PTS 12288
#define DIM   64
#define KSEL  16
#define CAPR  256        // per-row survivor capacity
#define TILES 6          // i-tiles (of 16 rows) per scan block
#define ZCUT  2.70f      // moment-model z; certificate+fallback cover the tail

typedef __bf16 bf16x8 __attribute__((ext_vector_type(8)));
typedef float  f32x4  __attribute__((ext_vector_type(4)));

// ---------------------------------------------------------------------------
// Stats: S1/S2/Sx moments, fp32+fp64 row norms, bf16 coords copy.
// ---------------------------------------------------------------------------
__global__ __launch_bounds__(256) void stats_kernel(
    const float* __restrict__ coords,
    float* __restrict__ s1, float* __restrict__ s2, float* __restrict__ sx,
    float* __restrict__ sq, double* __restrict__ sq64,
    __bf16* __restrict__ chi)
{
    __shared__ float colsh[4][64];
    const int lane = threadIdx.x & 63;
    const int wave = threadIdx.x >> 6;
    const int gw   = blockIdx.x * 4 + wave;     // 0..1023
    float colsum = 0.f, sqsum = 0.f, sq2sum = 0.f;
    for (int r = gw; r < N_PTS; r += 1024) {
        const float x = coords[r * DIM + lane];
        chi[r * DIM + lane] = (__bf16)x;
        colsum += x;
        float  p   = x * x;
        double p64 = (double)x * (double)x;
        #pragma unroll
        for (int off = 32; off > 0; off >>= 1) {
            p   += __shfl_xor(p, off, 64);
            p64 += __shfl_xor(p64, off, 64);
        }
        if (lane == 0) {
            sq[r] = p; sq64[r] = p64;
            sqsum += p; sq2sum += p * p;
        }
    }
    colsh[wave][lane] = colsum;
    __syncthreads();
    if (wave == 0) {
        const float c = colsh[0][lane] + colsh[1][lane]
                      + colsh[2][lane] + colsh[3][lane];
        atomicAdd(&sx[lane], c);
    }
    if (lane == 0) { atomicAdd(s1, sqsum); atomicAdd(s2, sq2sum); }
}

// ---------------------------------------------------------------------------
// tcalc: per-row emit constant ce[i] = (sq_i - T_i - 1)/2 and sqh[j]=sq_j/2.
//   emit   : acc >= ce[i] + sqh[j]        <=>  screen_d2 <= T+1
//   strict : acc >= ce[i] + sqh[j] + 1    <=>  screen_d2 <= T-1
// Certificate (strict>=17 incl self => true top-16 emitted) needs |screen
// err| <= 1; bf16 dot error is <~0.5 here.
// ---------------------------------------------------------------------------
__global__ __launch_bounds__(256) void tcalc_kernel(
    const float* __restrict__ sq,
    const float* __restrict__ s1, const float* __restrict__ s2,
    float* __restrict__ ce, float* __restrict__ sqh)
{
    const int r = (int)blockIdx.x * 256 + threadIdx.x;
    const float sqr    = sq[r];
    const float mu_sq  = s1[0] * (1.0f / N_PTS);
    const float var_sq = s2[0] * (1.0f / N_PTS) - mu_sq * mu_sq;
    const float mu  = sqr + mu_sq;
    const float sig = sqrtf(fmaxf(var_sq, 0.f) + 4.0f * sqr);
    const float T   = mu - ZCUT * sig;
    ce[r]  = (sqr - T - 1.0f) * 0.5f;
    sqh[r] = 0.5f * sqr;
}

// ---------------------------------------------------------------------------
// Scan (single N^2 pass): 96 i-rows (6 tiles) per block, wave scans 256 js.
// Per step: 2 prefetched A-loads amortized over 6 tiles x 2 MFMA; per
// candidate 1 add + 2 cmps (+1 cnt add); rare accepted j's atomic-appended.
// ---------------------------------------------------------------------------
__global__ __launch_bounds__(256) void scan_kernel(
    const __bf16* __restrict__ chi,
    const float* __restrict__ sqh, const float* __restrict__ ce,
    unsigned* __restrict__ ctrS, unsigned* __restrict__ ctrE,
    unsigned short* __restrict__ wsknn)      // [N][CAPR]
{
    const int lane = threadIdx.x & 63;
    const int wave = threadIdx.x >> 6;
    const int col  = lane & 15;
    const int quad = lane >> 4;
    const int ibase = (int)blockIdx.x * (16 * TILES);
    const bf16x8* cp = (const bf16x8*)chi;

    bf16x8 b0[TILES], b1[TILES];
    float cE[TILES]; int rowv[TILES]; int cnt[TILES];
    #pragma unroll
    for (int t = 0; t < TILES; ++t) {
        rowv[t] = ibase + 16 * t + col;
        b0[t] = cp[rowv[t] * 8 + quad];
        b1[t] = cp[rowv[t] * 8 + quad + 4];
        cE[t] = ce[rowv[t]];
        cnt[t] = 0;
    }

    const int jw = (int)blockIdx.y * 1024 + wave * 256;
    int arow = jw + col;
    bf16x8 a0n = cp[arow * 8 + quad];
    bf16x8 a1n = cp[arow * 8 + quad + 4];
    float4 hjn = *(const float4*)(sqh + jw + quad * 4);

    #pragma unroll 1
    for (int s = 0; s < 16; ++s) {
        const bf16x8 a0 = a0n, a1 = a1n;
        const float4 hj = hjn;
        const int j0 = jw + s * 16;
        if (s < 15) {                        // prefetch next step
            const int na = j0 + 16 + col;
            a0n = cp[na * 8 + quad];
            a1n = cp[na * 8 + quad + 4];
            hjn = *(const float4*)(sqh + j0 + 16 + quad * 4);
        }
        const int jb = j0 + quad * 4;
        #pragma unroll
        for (int t = 0; t < TILES; ++t) {
            f32x4 acc = {0.f, 0.f, 0.f, 0.f};
            acc = __builtin_amdgcn_mfma_f32_16x16x32_bf16(a0, b0[t], acc, 0, 0, 0);
            acc = __builtin_amdgcn_mfma_f32_16x16x32_bf16(a1, b1[t], acc, 0, 0, 0);
            const float th0 = cE[t] + hj.x, th1 = cE[t] + hj.y;
            const float th2 = cE[t] + hj.z, th3 = cE[t] + hj.w;
            cnt[t] += (acc[0] >= th0 + 1.f) + (acc[1] >= th1 + 1.f)
                    + (acc[2] >= th2 + 1.f) + (acc[3] >= th3 + 1.f);
            const bool e0 = acc[0] >= th0, e1 = acc[1] >= th1;
            const bool e2 = acc[2] >= th2, e3 = acc[3] >= th3;
            if (__any(e0 | e1 | e2 | e3)) {
                const int r = rowv[t];
                if (e0) { const unsigned p = atomicAdd(&ctrE[r], 1u);
                          if (p < CAPR) wsknn[r * CAPR + p] = (unsigned short)(jb + 0); }
                if (e1) { const unsigned p = atomicAdd(&ctrE[r], 1u);
                          if (p < CAPR) wsknn[r * CAPR + p] = (unsigned short)(jb + 1); }
                if (e2) { const unsigned p = atomicAdd(&ctrE[r], 1u);
                          if (p < CAPR) wsknn[r * CAPR + p] = (unsigned short)(jb + 2); }
                if (e3) { const unsigned p = atomicAdd(&ctrE[r], 1u);
                          if (p < CAPR) wsknn[r * CAPR + p] = (unsigned short)(jb + 3); }
            }
        }
    }
    #pragma unroll
    for (int t = 0; t < TILES; ++t) {        // quad-reduced strict counts
        int c = cnt[t];
        c += __shfl_xor(c, 16, 64);
        c += __shfl_xor(c, 32, 64);
        if (quad == 0) atomicAdd(&ctrS[rowv[t]], (unsigned)c);
    }
}

// ---------------------------------------------------------------------------
// Fallback: rows failing the certificate (strict<17) or overflowing CAPR get
// an exact fp32 full rescan -> top-24. Near-zero cost when nothing flagged.
// ---------------------------------------------------------------------------
__global__ __launch_bounds__(256) void fallback_kernel(
    const float* __restrict__ coords, const float* __restrict__ sq,
    const unsigned* __restrict__ ctrS,
    unsigned* __restrict__ ctrE, unsigned short* __restrict__ wsknn)
{
    __shared__ float d2s[N_PTS];
    __shared__ unsigned char flg[64];
    __shared__ float rv[4]; __shared__ int ri[4];
    const int tid = threadIdx.x;
    const int rbase = (int)blockIdx.x * 64;
    if (tid < 64)
        flg[tid] = (ctrS[rbase + tid] < 17u || ctrE[rbase + tid] > CAPR) ? 1 : 0;
    __syncthreads();
    #pragma unroll 1
    for (int rr = 0; rr < 64; ++rr) {
        if (!flg[rr]) continue;
        const int row = rbase + rr;
        float4 xi[16];
        const float4* xp = (const float4*)(coords + row * DIM);
        #pragma unroll
        for (int q = 0; q < 16; ++q) xi[q] = xp[q];
        const float sqr = sq[row];
        for (int j = tid; j < N_PTS; j += 256) {
            const float4* yp = (const float4*)(coords + j * DIM);
            float dot = 0.f;
            #pragma unroll
            for (int q = 0; q < 16; ++q) {
                const float4 b = yp[q];
                dot += xi[q].x * b.x + xi[q].y * b.y
                     + xi[q].z * b.z + xi[q].w * b.w;
            }
            d2s[j] = sqr + sq[j] - 2.f * dot;
        }
        __syncthreads();
        if (tid == 0) d2s[row] = 3e38f;
        __syncthreads();
        #pragma unroll 1
        for (int k = 0; k < 24; ++k) {
            float m = 3e38f; int mi = 0;
            for (int j = tid; j < N_PTS; j += 256)
                if (d2s[j] < m) { m = d2s[j]; mi = j; }
            #pragma unroll
            for (int off = 1; off < 64; off <<= 1) {
                const float om = __shfl_xor(m, off, 64);
                const int   oi = __shfl_xor(mi, off, 64);
                if (om < m || (om == m && oi < mi)) { m = om; mi = oi; }
            }
            if ((tid & 63) == 0) { rv[tid >> 6] = m; ri[tid >> 6] = mi; }
            __syncthreads();
            if (tid == 0) {
                float bm = rv[0]; int bi = ri[0];
                for (int u = 1; u < 4; ++u)
                    if (rv[u] < bm || (rv[u] == bm && ri[u] < bi)) {
                        bm = rv[u]; bi = ri[u];
                    }
                wsknn[row * CAPR + k] = (unsigned short)bi;
                d2s[bi] = 3e38f;
            }
            __syncthreads();
        }
        if (tid == 0) ctrE[row] = 24;
        __syncthreads();
    }
}

// ---------------------------------------------------------------------------
// Merge: wave per row. Dynamic ceil(L/64) fp64-refine batches (typ. 1),
// rank by LDS broadcast-count, exp only on rank<16, fp64 laplacian, fp32 out.
// ---------------------------------------------------------------------------
__global__ __launch_bounds__(256) void merge_kernel(
    const float* __restrict__ coords,
    const float* __restrict__ pot,
    const double* __restrict__ sq64,
    const float* __restrict__ s1, const float* __restrict__ sx,
    const unsigned* __restrict__ ctrE,
    const unsigned short* __restrict__ wsknn,
    float* __restrict__ out)
{
    __shared__ double sInv;
    __shared__ double ld2[4][CAPR];
    const int tid  = threadIdx.x;
    const int lane = tid & 63;
    const int wave = tid >> 6;
    const int row  = (int)blockIdx.x * 4 + wave;

    if (tid == 0) {
        double S1 = (double)s1[0], m2 = 0.0;
        for (int d = 0; d < DIM; ++d) { double t = (double)sx[d]; m2 += t * t; }
        const double NN = (double)N_PTS;
        sInv = 1.0 / ((2.0 * NN * S1 - 2.0 * m2) / (NN * NN)
                      + 1e-5 + 1e6 / NN + 1e-5);
    }

    const int L  = min((int)ctrE[row], CAPR);
    const int nb = (L + 63) >> 6;
    const double sqi = sq64[row];
    const float4* xip = (const float4*)(coords + row * DIM);

    double dreg[4]; int jreg[4];
    #pragma unroll 1
    for (int b = 0; b < nb; ++b) {
        const int t = b * 64 + lane;
        const int j = (t < L) ? (int)wsknn[row * CAPR + t] : row;
        const float4* xjp = (const float4*)(coords + j * DIM);
        double dot = 0.0;
        #pragma unroll
        for (int q = 0; q < 16; ++q) {
            const float4 a = xip[q], bb = xjp[q];
            dot += (double)a.x * (double)bb.x + (double)a.y * (double)bb.y
                 + (double)a.z * (double)bb.z + (double)a.w * (double)bb.w;
        }
        double d2 = sqi + sq64[j] + 1e-5 - 2.0 * dot;
        if (j == row || t >= L) d2 = 1e300;
        ld2[wave][t] = d2;
        dreg[b] = d2; jreg[b] = j;
    }
    __syncthreads();

    const double inv = sInv;
    const double vr  = (double)pot[row];
    double lap = 0.0;
    #pragma unroll 1
    for (int b = 0; b < nb; ++b) {
        const double d2 = dreg[b];
        const int t = b * 64 + lane;
        if (t < L && d2 < 1e299) {
            int rank = 0;
            #pragma unroll 1
            for (int m = 0; m < L; ++m) {
                const double o = ld2[wave][m];
                rank += (o < d2 || (o == d2 && m < t)) ? 1 : 0;
            }
            if (rank < KSEL)
                lap += exp(-d2 * inv) * ((double)pot[jreg[b]] - vr);
        }
    }
    #pragma unroll
    for (int off = 1; off < 64; off <<= 1)
        lap += __shfl_xor(lap, off, 64);
    if (lane == 0) out[row] = (float)lap;
}

extern "C" void kernel_launch(void* const* d_in, const int* in_sizes, int n_in,
                              void* d_out, int out_size, void* d_ws, size_t ws_size,
                              hipStream_t stream)
{
    (void)in_sizes; (void)n_in; (void)out_size; (void)ws_size;
    const float* coords = (const float*)d_in[0];
    const float* pot    = (const float*)d_in[1];
    // d_in[2] is k (always 16, compiled in as KSEL)

    char* w = (char*)d_ws;
    float*    s1   = (float*)w;                        // @0
    float*    s2   = (float*)(w + 4);                  // @4
    float*    sx   = (float*)(w + 16);                 // @16      [64]
    unsigned* ctrS = (unsigned*)(w + 512);             // @512     [N]
    unsigned* ctrE = (unsigned*)(w + 49664);           // @49664   [N]
    float*    sq   = (float*)(w + 98816);              // @98816   [N]
    float*    sqh  = (float*)(w + 147968);             // @147968  [N]
    float*    ce   = (float*)(w + 197120);             // @197120  [N]
    double*   sq64 = (double*)(w + 246272);            // @246272  [N]
    __bf16*   chi  = (__bf16*)(w + 344576);            // @344576  [N*64]
    unsigned short* wsknn = (unsigned short*)(w + 1917440); // [N*CAPR]
    // total = 8,208,896 B (round-7 proved ws_size >= 8,946,176)

    hipMemsetAsync(w, 0, 98816, stream);               // s1,s2,sx,ctrS,ctrE
    stats_kernel<<<dim3(256), dim3(256), 0, stream>>>(
        coords, s1, s2, sx, sq, sq64, chi);
    tcalc_kernel<<<dim3(N_PTS / 256), dim3(256), 0, stream>>>(
        sq, s1, s2, ce, sqh);
    scan_kernel<<<dim3(N_PTS / (16 * TILES), 12), dim3(256), 0, stream>>>(
        chi, sqh, ce, ctrS, ctrE, wsknn);
    fallback_kernel<<<dim3(N_PTS / 64), dim3(256), 0, stream>>>(
        coords, sq, ctrS, ctrE, wsknn);
    merge_kernel<<<dim3(N_PTS / 4), dim3(256), 0, stream>>>(
        coords, pot, sq64, s1, sx, ctrE, wsknn, (float*)d_out);
}

// Round 9
// 301.913 us; speedup vs baseline: 34.4902x; 34.4902x over previous
//
#include <hip/hip_runtime.h>
#include <hip/hip_bf16.h>

#define N_PTS 12288
#define DIM   64
#define KSEL  16
#define CAPR  256        // per-row survivor capacity
#define TILES 6          // i-tiles (of 16 rows) per scan block
#define ZCUT  2.35f      // strict-count mean ~100 >> 17: 5x model-error margin

typedef __bf16 bf16x8 __attribute__((ext_vector_type(8)));
typedef float  f32x4  __attribute__((ext_vector_type(4)));

// ---------------------------------------------------------------------------
// Stats: S1/S2/Sx moments, fp32+fp64 row norms, bf16 coords copy.
// ---------------------------------------------------------------------------
__global__ __launch_bounds__(256) void stats_kernel(
    const float* __restrict__ coords,
    float* __restrict__ s1, float* __restrict__ s2, float* __restrict__ sx,
    float* __restrict__ sq, double* __restrict__ sq64,
    __bf16* __restrict__ chi)
{
    __shared__ float colsh[4][64];
    const int lane = threadIdx.x & 63;
    const int wave = threadIdx.x >> 6;
    const int gw   = blockIdx.x * 4 + wave;     // 0..1023
    float colsum = 0.f, sqsum = 0.f, sq2sum = 0.f;
    for (int r = gw; r < N_PTS; r += 1024) {
        const float x = coords[r * DIM + lane];
        chi[r * DIM + lane] = (__bf16)x;
        colsum += x;
        float  p   = x * x;
        double p64 = (double)x * (double)x;
        #pragma unroll
        for (int off = 32; off > 0; off >>= 1) {
            p   += __shfl_xor(p, off, 64);
            p64 += __shfl_xor(p64, off, 64);
        }
        if (lane == 0) {
            sq[r] = p; sq64[r] = p64;
            sqsum += p; sq2sum += p * p;
        }
    }
    colsh[wave][lane] = colsum;
    __syncthreads();
    if (wave == 0) {
        const float c = colsh[0][lane] + colsh[1][lane]
                      + colsh[2][lane] + colsh[3][lane];
        atomicAdd(&sx[lane], c);
    }
    if (lane == 0) { atomicAdd(s1, sqsum); atomicAdd(s2, sq2sum); }
}

// ---------------------------------------------------------------------------
// tcalc: per-row emit constant ce[i] = (sq_i - T_i - 1)/2 and sqh[j]=sq_j/2.
//   emit   : dot >= ce[i] + sqh[j]       <=>  screen_d2 <= T+1
//   strict : dot >= ce[i] + sqh[j] + 1   <=>  screen_d2 <= T-1
// Certificate (strict>=17 incl self => true top-16 emitted) needs
// |screen_d2 - true_d2| <= 1; bf16-dot error here is <~0.6 worst-case.
// ---------------------------------------------------------------------------
__global__ __launch_bounds__(256) void tcalc_kernel(
    const float* __restrict__ sq,
    const float* __restrict__ s1, const float* __restrict__ s2,
    float* __restrict__ ce, float* __restrict__ sqh)
{
    const int r = (int)blockIdx.x * 256 + threadIdx.x;
    const float sqr    = sq[r];
    const float mu_sq  = s1[0] * (1.0f / N_PTS);
    const float var_sq = s2[0] * (1.0f / N_PTS) - mu_sq * mu_sq;
    const float mu  = sqr + mu_sq;
    const float sig = sqrtf(fmaxf(var_sq, 0.f) + 4.0f * sqr);
    const float T   = fmaxf(mu - ZCUT * sig, 2.0f);
    ce[r]  = (sqr - T - 1.0f) * 0.5f;
    sqh[r] = 0.5f * sqr;
}

// ---------------------------------------------------------------------------
// Scan (single N^2 pass): 96 i-rows (6 tiles) per block, wave scans 256 js.
// Per step: 2 prefetched A-loads amortized over 6 tiles x 2 MFMA; per
// candidate 1 add + 2 cmps (+1 cnt add); accepted j's atomic-appended.
// ---------------------------------------------------------------------------
__global__ __launch_bounds__(256) void scan_kernel(
    const __bf16* __restrict__ chi,
    const float* __restrict__ sqh, const float* __restrict__ ce,
    unsigned* __restrict__ ctrS, unsigned* __restrict__ ctrE,
    unsigned short* __restrict__ wsknn)      // [N][CAPR]
{
    const int lane = threadIdx.x & 63;
    const int wave = threadIdx.x >> 6;
    const int col  = lane & 15;
    const int quad = lane >> 4;
    const int ibase = (int)blockIdx.x * (16 * TILES);
    const bf16x8* cp = (const bf16x8*)chi;

    bf16x8 b0[TILES], b1[TILES];
    float cE[TILES]; int rowv[TILES]; int cnt[TILES];
    #pragma unroll
    for (int t = 0; t < TILES; ++t) {
        rowv[t] = ibase + 16 * t + col;
        b0[t] = cp[rowv[t] * 8 + quad];
        b1[t] = cp[rowv[t] * 8 + quad + 4];
        cE[t] = ce[rowv[t]];
        cnt[t] = 0;
    }

    const int jw = (int)blockIdx.y * 1024 + wave * 256;
    bf16x8 a0n = cp[(jw + col) * 8 + quad];
    bf16x8 a1n = cp[(jw + col) * 8 + quad + 4];
    float4 hjn = *(const float4*)(sqh + jw + quad * 4);

    #pragma unroll 1
    for (int s = 0; s < 16; ++s) {
        const bf16x8 a0 = a0n, a1 = a1n;
        const float4 hj = hjn;
        const int j0 = jw + s * 16;
        if (s < 15) {                        // prefetch next step
            const int na = j0 + 16 + col;
            a0n = cp[na * 8 + quad];
            a1n = cp[na * 8 + quad + 4];
            hjn = *(const float4*)(sqh + j0 + 16 + quad * 4);
        }
        const int jb = j0 + quad * 4;
        #pragma unroll
        for (int t = 0; t < TILES; ++t) {
            f32x4 acc = {0.f, 0.f, 0.f, 0.f};
            acc = __builtin_amdgcn_mfma_f32_16x16x32_bf16(a0, b0[t], acc, 0, 0, 0);
            acc = __builtin_amdgcn_mfma_f32_16x16x32_bf16(a1, b1[t], acc, 0, 0, 0);
            const float th0 = cE[t] + hj.x, th1 = cE[t] + hj.y;
            const float th2 = cE[t] + hj.z, th3 = cE[t] + hj.w;
            cnt[t] += (acc[0] >= th0 + 1.f) + (acc[1] >= th1 + 1.f)
                    + (acc[2] >= th2 + 1.f) + (acc[3] >= th3 + 1.f);
            const bool e0 = acc[0] >= th0, e1 = acc[1] >= th1;
            const bool e2 = acc[2] >= th2, e3 = acc[3] >= th3;
            if (__any(e0 | e1 | e2 | e3)) {
                const int r = rowv[t];
                if (e0) { const unsigned p = atomicAdd(&ctrE[r], 1u);
                          if (p < CAPR) wsknn[r * CAPR + p] = (unsigned short)(jb + 0); }
                if (e1) { const unsigned p = atomicAdd(&ctrE[r], 1u);
                          if (p < CAPR) wsknn[r * CAPR + p] = (unsigned short)(jb + 1); }
                if (e2) { const unsigned p = atomicAdd(&ctrE[r], 1u);
                          if (p < CAPR) wsknn[r * CAPR + p] = (unsigned short)(jb + 2); }
                if (e3) { const unsigned p = atomicAdd(&ctrE[r], 1u);
                          if (p < CAPR) wsknn[r * CAPR + p] = (unsigned short)(jb + 3); }
            }
        }
    }
    #pragma unroll
    for (int t = 0; t < TILES; ++t) {        // quad-reduced strict counts
        int c = cnt[t];
        c += __shfl_xor(c, 16, 64);
        c += __shfl_xor(c, 32, 64);
        if (quad == 0) atomicAdd(&ctrS[rowv[t]], (unsigned)c);
    }
}

// ---------------------------------------------------------------------------
// Fallback: rows failing the certificate (strict<17) or overflowing CAPR get
// an exact fp32 full rescan -> top-24. Expected ~never at z=2.35.
// ---------------------------------------------------------------------------
__global__ __launch_bounds__(256) void fallback_kernel(
    const float* __restrict__ coords, const float* __restrict__ sq,
    const unsigned* __restrict__ ctrS,
    unsigned* __restrict__ ctrE, unsigned short* __restrict__ wsknn)
{
    __shared__ float d2s[N_PTS];
    __shared__ unsigned char flg[64];
    __shared__ float rv[4]; __shared__ int ri[4];
    const int tid = threadIdx.x;
    const int rbase = (int)blockIdx.x * 64;
    if (tid < 64)
        flg[tid] = (ctrS[rbase + tid] < 17u || ctrE[rbase + tid] > CAPR) ? 1 : 0;
    __syncthreads();
    #pragma unroll 1
    for (int rr = 0; rr < 64; ++rr) {
        if (!flg[rr]) continue;
        const int row = rbase + rr;
        float4 xi[16];
        const float4* xp = (const float4*)(coords + row * DIM);
        #pragma unroll
        for (int q = 0; q < 16; ++q) xi[q] = xp[q];
        const float sqr = sq[row];
        for (int j = tid; j < N_PTS; j += 256) {
            const float4* yp = (const float4*)(coords + j * DIM);
            float dot = 0.f;
            #pragma unroll
            for (int q = 0; q < 16; ++q) {
                const float4 b = yp[q];
                dot += xi[q].x * b.x + xi[q].y * b.y
                     + xi[q].z * b.z + xi[q].w * b.w;
            }
            d2s[j] = sqr + sq[j] - 2.f * dot;
        }
        __syncthreads();
        if (tid == 0) d2s[row] = 3e38f;
        __syncthreads();
        #pragma unroll 1
        for (int k = 0; k < 24; ++k) {
            float m = 3e38f; int mi = 0;
            for (int j = tid; j < N_PTS; j += 256)
                if (d2s[j] < m) { m = d2s[j]; mi = j; }
            #pragma unroll
            for (int off = 1; off < 64; off <<= 1) {
                const float om = __shfl_xor(m, off, 64);
                const int   oi = __shfl_xor(mi, off, 64);
                if (om < m || (om == m && oi < mi)) { m = om; mi = oi; }
            }
            if ((tid & 63) == 0) { rv[tid >> 6] = m; ri[tid >> 6] = mi; }
            __syncthreads();
            if (tid == 0) {
                float bm = rv[0]; int bi = ri[0];
                for (int u = 1; u < 4; ++u)
                    if (rv[u] < bm || (rv[u] == bm && ri[u] < bi)) {
                        bm = rv[u]; bi = ri[u];
                    }
                wsknn[row * CAPR + k] = (unsigned short)bi;
                d2s[bi] = 3e38f;
            }
            __syncthreads();
        }
        if (tid == 0) ctrE[row] = 24;
        __syncthreads();
    }
}

// ---------------------------------------------------------------------------
// Merge: wave per row. ceil(L/64) fp64-refine batches (statically unrolled,
// guarded), rank by LDS broadcast-count, exp only on rank<16, fp64 laplacian.
// ---------------------------------------------------------------------------
__global__ __launch_bounds__(256) void merge_kernel(
    const float* __restrict__ coords,
    const float* __restrict__ pot,
    const double* __restrict__ sq64,
    const float* __restrict__ s1, const float* __restrict__ sx,
    const unsigned* __restrict__ ctrE,
    const unsigned short* __restrict__ wsknn,
    float* __restrict__ out)
{
    __shared__ double sInv;
    __shared__ double ld2[4][CAPR];
    const int tid  = threadIdx.x;
    const int lane = tid & 63;
    const int wave = tid >> 6;
    const int row  = (int)blockIdx.x * 4 + wave;

    if (tid == 0) {
        double S1 = (double)s1[0], m2 = 0.0;
        for (int d = 0; d < DIM; ++d) { double t = (double)sx[d]; m2 += t * t; }
        const double NN = (double)N_PTS;
        sInv = 1.0 / ((2.0 * NN * S1 - 2.0 * m2) / (NN * NN)
                      + 1e-5 + 1e6 / NN + 1e-5);
    }

    const int L  = min((int)ctrE[row], CAPR);
    const int nb = (L + 63) >> 6;
    const double sqi = sq64[row];
    const float4* xip = (const float4*)(coords + row * DIM);

    double dreg[4]; int jreg[4];
    #pragma unroll
    for (int b = 0; b < 4; ++b) {
        dreg[b] = 1e300; jreg[b] = row;
        if (b < nb) {
            const int t = b * 64 + lane;
            const int j = (t < L) ? (int)wsknn[row * CAPR + t] : row;
            const float4* xjp = (const float4*)(coords + j * DIM);
            double dot = 0.0;
            #pragma unroll
            for (int q = 0; q < 16; ++q) {
                const float4 a = xip[q], bb = xjp[q];
                dot += (double)a.x * (double)bb.x + (double)a.y * (double)bb.y
                     + (double)a.z * (double)bb.z + (double)a.w * (double)bb.w;
            }
            double d2 = sqi + sq64[j] + 1e-5 - 2.0 * dot;
            if (j == row || t >= L) d2 = 1e300;
            ld2[wave][t] = d2;
            dreg[b] = d2; jreg[b] = j;
        }
    }
    __syncthreads();

    const double inv = sInv;
    const double vr  = (double)pot[row];
    double lap = 0.0;
    #pragma unroll
    for (int b = 0; b < 4; ++b) {
        if (b < nb) {
            const double d2 = dreg[b];
            const int t = b * 64 + lane;
            if (t < L && d2 < 1e299) {
                int rank = 0;
                #pragma unroll 1
                for (int m = 0; m < L; ++m) {
                    const double o = ld2[wave][m];
                    rank += (o < d2 || (o == d2 && m < t)) ? 1 : 0;
                }
                if (rank < KSEL)
                    lap += exp(-d2 * inv) * ((double)pot[jreg[b]] - vr);
            }
        }
    }
    #pragma unroll
    for (int off = 1; off < 64; off <<= 1)
        lap += __shfl_xor(lap, off, 64);
    if (lane == 0) out[row] = (float)lap;
}

extern "C" void kernel_launch(void* const* d_in, const int* in_sizes, int n_in,
                              void* d_out, int out_size, void* d_ws, size_t ws_size,
                              hipStream_t stream)
{
    (void)in_sizes; (void)n_in; (void)out_size; (void)ws_size;
    const float* coords = (const float*)d_in[0];
    const float* pot    = (const float*)d_in[1];
    // d_in[2] is k (always 16, compiled in as KSEL)

    char* w = (char*)d_ws;
    float*    s1   = (float*)w;                        // @0
    float*    s2   = (float*)(w + 4);                  // @4
    float*    sx   = (float*)(w + 16);                 // @16      [64]
    unsigned* ctrS = (unsigned*)(w + 512);             // @512     [N]
    unsigned* ctrE = (unsigned*)(w + 49664);           // @49664   [N]
    float*    sq   = (float*)(w + 98816);              // @98816   [N]
    float*    sqh  = (float*)(w + 147968);             // @147968  [N]
    float*    ce   = (float*)(w + 197120);             // @197120  [N]
    double*   sq64 = (double*)(w + 246272);            // @246272  [N]
    __bf16*   chi  = (__bf16*)(w + 344576);            // @344576  [N*64]
    unsigned short* wsknn = (unsigned short*)(w + 1917440); // [N*CAPR]
    // total = 8,208,896 B (rounds 5-8 ran with layouts up to 9.05 MB)

    hipMemsetAsync(w, 0, 98816, stream);               // s1,s2,sx,ctrS,ctrE
    stats_kernel<<<dim3(256), dim3(256), 0, stream>>>(
        coords, s1, s2, sx, sq, sq64, chi);
    tcalc_kernel<<<dim3(N_PTS / 256), dim3(256), 0, stream>>>(
        sq, s1, s2, ce, sqh);
    scan_kernel<<<dim3(N_PTS / (16 * TILES), 12), dim3(256), 0, stream>>>(
        chi, sqh, ce, ctrS, ctrE, wsknn);
    fallback_kernel<<<dim3(N_PTS / 64), dim3(256), 0, stream>>>(
        coords, sq, ctrS, ctrE, wsknn);
    merge_kernel<<<dim3(N_PTS / 4), dim3(256), 0, stream>>>(
        coords, pot, sq64, s1, sx, ctrE, wsknn, (float*)d_out);
}